// Round 1
// baseline (518.355 us; speedup 1.0000x reference)
//
#include <hip/hip_runtime.h>
#include <cstddef>

#define N_NODES_C 50000
#define N_EDGES_C 800000

// LDS strides (floats). XSTR for X/H buffers (k-major, node minor),
// WTSTR for the transposed w_out slice. Both multiples of 4 so float4
// (ds_read_b128) stays 16B-aligned; offsets chosen to spread banks.
constexpr int XSTR  = 68;
constexpr int WTSTR = 36;

// ---------------------------------------------------------------------------
// Kernel A: per-node MLP -> q[n][y]
// Block = 256 threads, 64 nodes per block.
// Layout: Xc[x][n], H[k][n] (k-major so reads along n vectorize to b128).
// w_out stage: for each k, V_k[y][n] = sum_x w_out[k][y*64+x] * x[n][x],
//              q[n][y] += h[n][k] * V_k[y][n];  bias handled as extra "k"
//              with h == 1 and W row = b_out.
// ---------------------------------------------------------------------------
__launch_bounds__(256, 2)
__global__ void mlp_q_kernel(const float* __restrict__ xf,
                             const float* __restrict__ w_in,
                             const float* __restrict__ b_in,
                             const float* __restrict__ w_mid,
                             const float* __restrict__ b_mid,
                             const float* __restrict__ w_out,
                             const float* __restrict__ b_out,
                             float* __restrict__ q)
{
    __shared__ float Xc[64 * XSTR];        // X transposed: Xc[x][n]
    __shared__ float H0[64 * XSTR];        // h ping
    __shared__ float H1[64 * XSTR];        // h pong; later reused as Qlds[2][32][XSTR]
    __shared__ float Wbuf[2 * 64 * WTSTR]; // union: layer W [k*64+j] | Wt[kk][x][y]
    __shared__ float bbuf[64];

    const int t = threadIdx.x;
    const int node0 = blockIdx.x * 64;

    // ---- stage X tile, transposed ----
    {
        const int n = t >> 2;
        const int nglob = min(node0 + n, N_NODES_C - 1);
        const float4* src = (const float4*)(xf + (size_t)nglob * 64);
        #pragma unroll
        for (int i = 0; i < 4; ++i) {
            const int x4 = (t & 3) + i * 4;      // float4 index 0..15
            const float4 v = src[x4];
            const int x = x4 * 4;
            Xc[(x + 0) * XSTR + n] = v.x;
            Xc[(x + 1) * XSTR + n] = v.y;
            Xc[(x + 2) * XSTR + n] = v.z;
            Xc[(x + 3) * XSTR + n] = v.w;
        }
    }

    // ---- 7 dense layers: h = relu(h @ W + b) ----
    {
        const int ng = t & 15;     // node group (4 nodes)
        const int jg = t >> 4;     // output group (4 outputs)
        const float* Hsrc = Xc;
        float* Hdst = H0;
        for (int layer = 0; layer < 7; ++layer) {
            const float* wsrc = (layer == 0) ? w_in : (w_mid + (size_t)(layer - 1) * 4096);
            const float* bsrc = (layer == 0) ? b_in : (b_mid + (size_t)(layer - 1) * 64);
            __syncthreads();   // previous layer's readers of Wbuf done
            {
                const float4* ws4 = (const float4*)wsrc;
                float4* wd4 = (float4*)Wbuf;
                #pragma unroll
                for (int s = 0; s < 4; ++s) wd4[t + 256 * s] = ws4[t + 256 * s];
                if (t < 16) ((float4*)bbuf)[t] = ((const float4*)bsrc)[t];
            }
            __syncthreads();

            float acc[4][4];
            #pragma unroll
            for (int j = 0; j < 4; ++j) {
                const float bj = bbuf[jg * 4 + j];
                #pragma unroll
                for (int i = 0; i < 4; ++i) acc[j][i] = bj;
            }
            #pragma unroll 4
            for (int k = 0; k < 64; ++k) {
                const float4 hv = *(const float4*)&Hsrc[k * XSTR + ng * 4];
                const float4 wv = *(const float4*)&Wbuf[k * 64 + jg * 4];
                const float hv_[4] = {hv.x, hv.y, hv.z, hv.w};
                const float wv_[4] = {wv.x, wv.y, wv.z, wv.w};
                #pragma unroll
                for (int j = 0; j < 4; ++j)
                    #pragma unroll
                    for (int i = 0; i < 4; ++i)
                        acc[j][i] = fmaf(hv_[i], wv_[j], acc[j][i]);
            }
            #pragma unroll
            for (int j = 0; j < 4; ++j) {
                float4 o;
                o.x = fmaxf(acc[j][0], 0.f);
                o.y = fmaxf(acc[j][1], 0.f);
                o.z = fmaxf(acc[j][2], 0.f);
                o.w = fmaxf(acc[j][3], 0.f);
                *(float4*)&Hdst[(jg * 4 + j) * XSTR + ng * 4] = o;
            }
            Hsrc = Hdst;
            Hdst = (Hdst == H0) ? H1 : H0;
        }
        // final h lives in H0; H1 is free
    }

    // ---- w_out stage: q[n][y] = sum_k h[n][k] * (w_out[k] . x[n]) + b_out . x[n]
    {
        const int kk = t >> 7;       // which of 2 k's this thread computes
        const int r  = t & 127;
        const int yg = r & 7;        // 8 groups of 4 y   (32 y)
        const int ng = r >> 3;       // 16 groups of 4 n  (64 n)
        float qacc[4][4];
        #pragma unroll
        for (int j = 0; j < 4; ++j)
            #pragma unroll
            for (int i = 0; i < 4; ++i) qacc[j][i] = 0.f;

        const float* Hfin = H0;
        for (int iter = 0; iter < 33; ++iter) {
            __syncthreads();   // previous iter's readers of Wbuf done
            // stage 2 rows of w_out (or b_out) transposed into Wt[kf][x][y]
            #pragma unroll
            for (int s = 0; s < 4; ++s) {
                const int f4 = t + 256 * s;       // 0..1023 float4s
                const int kf = f4 >> 9;           // 0/1
                const int rem4 = f4 & 511;
                float4 v;
                if (iter < 32) {
                    v = ((const float4*)(w_out + (size_t)(iter * 2 + kf) * 2048))[rem4];
                } else if (kf == 0) {
                    v = ((const float4*)b_out)[rem4];
                } else {
                    v = make_float4(0.f, 0.f, 0.f, 0.f);
                }
                const int f = rem4 * 4;
                const int y = f >> 6;
                const int x = f & 63;
                float* wt = Wbuf + kf * (64 * WTSTR);
                wt[(x + 0) * WTSTR + y] = v.x;
                wt[(x + 1) * WTSTR + y] = v.y;
                wt[(x + 2) * WTSTR + y] = v.z;
                wt[(x + 3) * WTSTR + y] = v.w;
            }
            __syncthreads();

            float vacc[4][4];
            #pragma unroll
            for (int j = 0; j < 4; ++j)
                #pragma unroll
                for (int i = 0; i < 4; ++i) vacc[j][i] = 0.f;

            const float* wt = Wbuf + kk * (64 * WTSTR);
            #pragma unroll 4
            for (int x = 0; x < 64; ++x) {
                const float4 wv = *(const float4*)&wt[x * WTSTR + yg * 4];
                const float4 xv = *(const float4*)&Xc[x * XSTR + ng * 4];
                const float wv_[4] = {wv.x, wv.y, wv.z, wv.w};
                const float xv_[4] = {xv.x, xv.y, xv.z, xv.w};
                #pragma unroll
                for (int j = 0; j < 4; ++j)
                    #pragma unroll
                    for (int i = 0; i < 4; ++i)
                        vacc[j][i] = fmaf(wv_[j], xv_[i], vacc[j][i]);
            }

            float4 hv;
            if (iter < 32) {
                hv = *(const float4*)&Hfin[(iter * 2 + kk) * XSTR + ng * 4];
            } else {
                hv = (kk == 0) ? make_float4(1.f, 1.f, 1.f, 1.f)
                               : make_float4(0.f, 0.f, 0.f, 0.f);
            }
            const float hv_[4] = {hv.x, hv.y, hv.z, hv.w};
            #pragma unroll
            for (int j = 0; j < 4; ++j)
                #pragma unroll
                for (int i = 0; i < 4; ++i)
                    qacc[j][i] = fmaf(hv_[i], vacc[j][i], qacc[j][i]);
        }

        // partial q to LDS (reuse H1): Qlds[kk][y][n]
        float* Qlds = H1;
        #pragma unroll
        for (int j = 0; j < 4; ++j) {
            const float4 o = {qacc[j][0], qacc[j][1], qacc[j][2], qacc[j][3]};
            *(float4*)&Qlds[kk * (32 * XSTR) + (yg * 4 + j) * XSTR + ng * 4] = o;
        }
    }
    __syncthreads();

    // ---- combine the two k-partials and store q (coalesced) ----
    {
        const int y  = t & 31;
        const int n8 = t >> 5;     // 0..7
        #pragma unroll
        for (int i = 0; i < 8; ++i) {
            const int n = n8 * 8 + i;
            const float v = H1[y * XSTR + n] + H1[32 * XSTR + y * XSTR + n];
            const int ngl = node0 + n;
            if (ngl < N_NODES_C) q[(size_t)ngl * 32 + y] = v;
        }
    }
}

// ---------------------------------------------------------------------------
// Edge kernels
// ---------------------------------------------------------------------------
__global__ void deg_kernel(const int* __restrict__ col, int* __restrict__ deg)
{
    const int e = blockIdx.x * 256 + threadIdx.x;
    if (e < N_EDGES_C) atomicAdd(&deg[col[e]], 1);
}

__global__ void dinv_kernel(const int* __restrict__ deg, float* __restrict__ dinv)
{
    const int i = blockIdx.x * 256 + threadIdx.x;
    if (i < N_NODES_C) {
        const int d = deg[i];
        dinv[i] = (d > 0) ? rsqrtf((float)d) : 0.f;
    }
}

__global__ void scatter_kernel(const int* __restrict__ row,
                               const int* __restrict__ col,
                               const float* __restrict__ dinv,
                               const float* __restrict__ q,
                               float* __restrict__ out)
{
    const int tid = blockIdx.x * 256 + threadIdx.x;
    const int e = tid >> 5;
    const int y = tid & 31;
    if (e < N_EDGES_C) {
        const int rr = row[e];
        const int cc = col[e];
        const float nrm = dinv[rr] * dinv[cc];
        atomicAdd(&out[(size_t)cc * 32 + y], nrm * q[(size_t)rr * 32 + y]);
    }
}

// ---------------------------------------------------------------------------
extern "C" void kernel_launch(void* const* d_in, const int* in_sizes, int n_in,
                              void* d_out, int out_size, void* d_ws, size_t ws_size,
                              hipStream_t stream)
{
    const float* xf    = (const float*)d_in[0];
    const int*   eidx  = (const int*)d_in[1];
    const float* w_in  = (const float*)d_in[2];
    const float* b_in  = (const float*)d_in[3];
    const float* w_mid = (const float*)d_in[4];
    const float* b_mid = (const float*)d_in[5];
    const float* w_out = (const float*)d_in[6];
    const float* b_out = (const float*)d_in[7];
    float* out = (float*)d_out;

    const int* row = eidx;
    const int* col = eidx + N_EDGES_C;

    // workspace layout
    float* q    = (float*)d_ws;                       // 50000*32 floats
    int*   deg  = (int*)(q + (size_t)N_NODES_C * 32); // 50000 ints
    float* dinv = (float*)(deg + N_NODES_C);          // 50000 floats

    hipMemsetAsync(deg, 0, N_NODES_C * sizeof(int), stream);
    hipMemsetAsync(out, 0, (size_t)out_size * sizeof(float), stream);

    mlp_q_kernel<<<dim3((N_NODES_C + 63) / 64), dim3(256), 0, stream>>>(
        xf, w_in, b_in, w_mid, b_mid, w_out, b_out, q);

    deg_kernel<<<dim3((N_EDGES_C + 255) / 256), dim3(256), 0, stream>>>(col, deg);
    dinv_kernel<<<dim3((N_NODES_C + 255) / 256), dim3(256), 0, stream>>>(deg, dinv);
    scatter_kernel<<<dim3((N_EDGES_C * 32) / 256), dim3(256), 0, stream>>>(
        row, col, dinv, q, out);
}

// Round 2
// 346.875 us; speedup vs baseline: 1.4944x; 1.4944x over previous
//
#include <hip/hip_runtime.h>
#include <cstddef>

#define N_NODES_C 50000
#define N_EDGES_C 800000

typedef _Float16 f16x8 __attribute__((ext_vector_type(8)));
typedef float    f32x4 __attribute__((ext_vector_type(4)));

// LDS row strides (elements)
constexpr int XSTR = 72;   // f16 rows for x / h buffers (bank-friendly: 2-way max)
constexpr int HSTR = 84;   // f32 rows for final-h buffer (k padded 64->80, stride 84)

// ---------------------------------------------------------------------------
// Prep: transposed f16 layer weights wT[l][j][k] = W_l[k][j], and
// W3[(y*80+k)][x] f16 = w_out[k][y*64+x] (k<64), b_out[y*64+x] (k==64), 0 pad.
// ---------------------------------------------------------------------------
__global__ void prep_kernel(const float* __restrict__ w_in,
                            const float* __restrict__ w_mid,
                            const float* __restrict__ w_out,
                            const float* __restrict__ b_out,
                            _Float16* __restrict__ wT,
                            _Float16* __restrict__ W3)
{
    const int idx = blockIdx.x * 256 + threadIdx.x;
    if (idx < 7 * 4096) {
        const int l = idx >> 12, rem = idx & 4095;
        const int j = rem >> 6, k = rem & 63;
        const float v = (l == 0) ? w_in[k * 64 + j]
                                 : w_mid[(size_t)(l - 1) * 4096 + k * 64 + j];
        wT[(size_t)l * 4096 + j * 64 + k] = (_Float16)v;
    } else {
        const int i2 = idx - 7 * 4096;
        if (i2 < 2560 * 64) {
            const int r = i2 >> 6, x = i2 & 63;
            const int y = r / 80;
            const int k = r - y * 80;
            float v = 0.f;
            if (k < 64)       v = w_out[(size_t)k * 2048 + y * 64 + x];
            else if (k == 64) v = b_out[y * 64 + x];
            W3[(size_t)r * 64 + x] = (_Float16)v;
        }
    }
}

// ---------------------------------------------------------------------------
// Main fused kernel: 64 nodes/block, 256 threads (4 waves).
//  Stage 0: load x -> f16 LDS  xb[n][x]
//  Stage 1: 7 MFMA layers, wave w owns nodes [16w,16w+16); h f16 in LDS,
//           final h as f32 in hF with hF[n][64]=1, hF[n][65..79]=0 (bias fold)
//  Stage 2: wave w owns y in [8w,8w+8). T = W3_tile @ x (MFMA, nodes on cols),
//           q[n,y] = sum_k hF[n][k]*T[k,n] per-lane + 2 shfl-xor adds.
//           Stores qs = dinv[n]*q[n,y].
// ---------------------------------------------------------------------------
__launch_bounds__(256, 2)
__global__ void mlp_q_kernel(const float* __restrict__ xf,
                             const float* __restrict__ b_in,
                             const float* __restrict__ b_mid,
                             const _Float16* __restrict__ wT,
                             const _Float16* __restrict__ W3,
                             const float* __restrict__ dinv,
                             float* __restrict__ qs)
{
    __shared__ _Float16 xb[64 * XSTR];   // 9216 B
    __shared__ _Float16 hb[64 * XSTR];   // 9216 B
    __shared__ float    hF[64 * HSTR];   // 21504 B

    const int t    = threadIdx.x;
    const int w    = t >> 6;
    const int lane = t & 63;
    const int quad = lane >> 4;
    const int lrow = lane & 15;
    const int node0 = blockIdx.x * 64;

    // ---- stage 0: x -> f16 LDS ----
    {
        const int n = t >> 2;
        const int nglob = min(node0 + n, N_NODES_C - 1);
        const float4* src = (const float4*)(xf + (size_t)nglob * 64);
        #pragma unroll
        for (int i = 0; i < 4; ++i) {
            const int x4 = (t & 3) + i * 4;
            const float4 v = src[x4];
            const int x = x4 * 4;
            xb[n * XSTR + x + 0] = (_Float16)v.x;
            xb[n * XSTR + x + 1] = (_Float16)v.y;
            xb[n * XSTR + x + 2] = (_Float16)v.z;
            xb[n * XSTR + x + 3] = (_Float16)v.w;
        }
    }
    __syncthreads();

    // ---- stage 1: 7 layers ----
    const int myrow0 = w * 16;
    for (int l = 0; l < 7; ++l) {
        const _Float16* hsrc = (l == 0) ? xb : hb;
        const _Float16* wTl = wT + (size_t)l * 4096;
        const float* bsrc = (l == 0) ? b_in : (b_mid + (size_t)(l - 1) * 64);

        f16x8 B[4][2];
        float bias[4];
        #pragma unroll
        for (int Nt = 0; Nt < 4; ++Nt) {
            #pragma unroll
            for (int Ks = 0; Ks < 2; ++Ks)
                B[Nt][Ks] = *(const f16x8*)(wTl + (Nt * 16 + lrow) * 64 + Ks * 32 + quad * 8);
            bias[Nt] = bsrc[Nt * 16 + lrow];
        }
        const f16x8 A0 = *(const f16x8*)&hsrc[(myrow0 + lrow) * XSTR + quad * 8];
        const f16x8 A1 = *(const f16x8*)&hsrc[(myrow0 + lrow) * XSTR + 32 + quad * 8];

        #pragma unroll
        for (int Nt = 0; Nt < 4; ++Nt) {
            f32x4 C = {0.f, 0.f, 0.f, 0.f};
            C = __builtin_amdgcn_mfma_f32_16x16x32_f16(A0, B[Nt][0], C, 0, 0, 0);
            C = __builtin_amdgcn_mfma_f32_16x16x32_f16(A1, B[Nt][1], C, 0, 0, 0);
            const int j = Nt * 16 + lrow;
            #pragma unroll
            for (int r = 0; r < 4; ++r) {
                const int n = myrow0 + quad * 4 + r;
                float v = fmaxf(C[r] + bias[Nt], 0.f);
                if (l < 6) hb[n * XSTR + j] = (_Float16)v;
                else       hF[n * HSTR + j] = v;
            }
        }
        __syncthreads();
    }
    // bias-fold columns of hF
    {
        #pragma unroll
        for (int r = 0; r < 4; ++r) {
            const int n = myrow0 + quad * 4 + r;
            hF[n * HSTR + 64 + lrow] = (lrow == 0) ? 1.f : 0.f;
        }
    }
    __syncthreads();

    // ---- stage 2: bilinear via MFMA ----
    f16x8 BX[4][2];
    float dv[4];
    #pragma unroll
    for (int nt = 0; nt < 4; ++nt) {
        #pragma unroll
        for (int Ks = 0; Ks < 2; ++Ks)
            BX[nt][Ks] = *(const f16x8*)&xb[(nt * 16 + lrow) * XSTR + Ks * 32 + quad * 8];
        const int n = node0 + nt * 16 + lrow;
        dv[nt] = (n < N_NODES_C) ? dinv[n] : 0.f;
    }

    const int y0 = w * 8;
    float qv[4][8];

    #pragma unroll
    for (int yp = 0; yp < 4; ++yp) {
        const int ya = y0 + yp * 2;
        const int yb = ya + 1;
        float qa[4] = {0.f, 0.f, 0.f, 0.f};
        float qb[4] = {0.f, 0.f, 0.f, 0.f};

        #pragma unroll
        for (int Mt = 0; Mt < 5; ++Mt) {
            const _Float16* ra = W3 + (size_t)(ya * 80 + Mt * 16 + lrow) * 64;
            const _Float16* rb = W3 + (size_t)(yb * 80 + Mt * 16 + lrow) * 64;
            const f16x8 Aa0 = *(const f16x8*)(ra + quad * 8);
            const f16x8 Aa1 = *(const f16x8*)(ra + 32 + quad * 8);
            const f16x8 Ab0 = *(const f16x8*)(rb + quad * 8);
            const f16x8 Ab1 = *(const f16x8*)(rb + 32 + quad * 8);

            #pragma unroll
            for (int nt = 0; nt < 4; ++nt) {
                f32x4 Ca = {0.f, 0.f, 0.f, 0.f};
                Ca = __builtin_amdgcn_mfma_f32_16x16x32_f16(Aa0, BX[nt][0], Ca, 0, 0, 0);
                Ca = __builtin_amdgcn_mfma_f32_16x16x32_f16(Aa1, BX[nt][1], Ca, 0, 0, 0);
                f32x4 Cb = {0.f, 0.f, 0.f, 0.f};
                Cb = __builtin_amdgcn_mfma_f32_16x16x32_f16(Ab0, BX[nt][0], Cb, 0, 0, 0);
                Cb = __builtin_amdgcn_mfma_f32_16x16x32_f16(Ab1, BX[nt][1], Cb, 0, 0, 0);

                const float4 h4 = *(const float4*)&hF[(nt * 16 + lrow) * HSTR + Mt * 16 + quad * 4];
                qa[nt] += Ca[0] * h4.x + Ca[1] * h4.y + Ca[2] * h4.z + Ca[3] * h4.w;
                qb[nt] += Cb[0] * h4.x + Cb[1] * h4.y + Cb[2] * h4.z + Cb[3] * h4.w;
            }
        }
        #pragma unroll
        for (int nt = 0; nt < 4; ++nt) {
            float a = qa[nt];
            a += __shfl_xor(a, 16);
            a += __shfl_xor(a, 32);
            float b = qb[nt];
            b += __shfl_xor(b, 16);
            b += __shfl_xor(b, 32);
            qv[nt][yp * 2 + 0] = a;
            qv[nt][yp * 2 + 1] = b;
        }
    }

    // ---- store qs = dinv[n] * q ----
    #pragma unroll
    for (int nt = 0; nt < 4; ++nt) {
        const int n = node0 + nt * 16 + lrow;
        if (n < N_NODES_C) {
            if (quad == 0) {
                float4 s = {qv[nt][0] * dv[nt], qv[nt][1] * dv[nt],
                            qv[nt][2] * dv[nt], qv[nt][3] * dv[nt]};
                *(float4*)&qs[(size_t)n * 32 + y0] = s;
            }
            if (quad == 1) {
                float4 s = {qv[nt][4] * dv[nt], qv[nt][5] * dv[nt],
                            qv[nt][6] * dv[nt], qv[nt][7] * dv[nt]};
                *(float4*)&qs[(size_t)n * 32 + y0 + 4] = s;
            }
        }
    }
}

// ---------------------------------------------------------------------------
// Edge pipeline
// ---------------------------------------------------------------------------
__global__ void deg_kernel(const int* __restrict__ col, int* __restrict__ deg)
{
    const int e = blockIdx.x * 256 + threadIdx.x;
    if (e < N_EDGES_C) atomicAdd(&deg[col[e]], 1);
}

__global__ void dinv_kernel(const int* __restrict__ deg, float* __restrict__ dinv)
{
    const int i = blockIdx.x * 256 + threadIdx.x;
    if (i < N_NODES_C) {
        const int d = deg[i];
        dinv[i] = (d > 0) ? rsqrtf((float)d) : 0.f;
    }
}

__global__ void scatter_kernel(const int* __restrict__ row,
                               const int* __restrict__ col,
                               const float* __restrict__ qs,
                               float* __restrict__ out)
{
    const int tid = blockIdx.x * 256 + threadIdx.x;
    const int e = tid >> 5;
    const int y = tid & 31;
    if (e < N_EDGES_C) {
        const int rr = row[e];
        const int cc = col[e];
        atomicAdd(&out[(size_t)cc * 32 + y], qs[(size_t)rr * 32 + y]);
    }
}

__global__ void postscale_kernel(const float* __restrict__ dinv, float* __restrict__ out)
{
    const int idx = blockIdx.x * 256 + threadIdx.x;  // float4 index
    if (idx < N_NODES_C * 8) {
        float4 v = ((float4*)out)[idx];
        const float f = dinv[idx >> 3];
        v.x *= f; v.y *= f; v.z *= f; v.w *= f;
        ((float4*)out)[idx] = v;
    }
}

// ---------------------------------------------------------------------------
extern "C" void kernel_launch(void* const* d_in, const int* in_sizes, int n_in,
                              void* d_out, int out_size, void* d_ws, size_t ws_size,
                              hipStream_t stream)
{
    const float* xf    = (const float*)d_in[0];
    const int*   eidx  = (const int*)d_in[1];
    const float* w_in  = (const float*)d_in[2];
    const float* b_in  = (const float*)d_in[3];
    const float* w_mid = (const float*)d_in[4];
    const float* b_mid = (const float*)d_in[5];
    const float* w_out = (const float*)d_in[6];
    const float* b_out = (const float*)d_in[7];
    float* out = (float*)d_out;

    const int* row = eidx;
    const int* col = eidx + N_EDGES_C;

    // workspace layout (all 16B aligned)
    char* ws = (char*)d_ws;
    float*    qs   = (float*)ws;                               // 6,400,000 B
    int*      deg  = (int*)(ws + 6400000);                     //   200,000 B
    float*    dinv = (float*)(ws + 6600000);                   //   200,000 B
    _Float16* wT   = (_Float16*)(ws + 6800000);                //    57,344 B
    _Float16* W3   = (_Float16*)(ws + 6800000 + 57344);        //   327,680 B

    hipMemsetAsync(deg, 0, N_NODES_C * sizeof(int), stream);
    hipMemsetAsync(out, 0, (size_t)out_size * sizeof(float), stream);

    prep_kernel<<<dim3((7 * 4096 + 2560 * 64 + 255) / 256), dim3(256), 0, stream>>>(
        w_in, w_mid, w_out, b_out, wT, W3);

    deg_kernel<<<dim3((N_EDGES_C + 255) / 256), dim3(256), 0, stream>>>(col, deg);
    dinv_kernel<<<dim3((N_NODES_C + 255) / 256), dim3(256), 0, stream>>>(deg, dinv);

    mlp_q_kernel<<<dim3((N_NODES_C + 63) / 64), dim3(256), 0, stream>>>(
        xf, b_in, b_mid, wT, W3, dinv, qs);

    scatter_kernel<<<dim3((N_EDGES_C * 32) / 256), dim3(256), 0, stream>>>(
        row, col, qs, out);
    postscale_kernel<<<dim3((N_NODES_C * 8 + 255) / 256), dim3(256), 0, stream>>>(
        dinv, out);
}